// Round 9
// baseline (449.651 us; speedup 1.0000x reference)
//
#include <hip/hip_runtime.h>
#include <hip/hip_bf16.h>

#define TEMP_INV 14.285714285714286f     // 1/0.07
#define KL2E     20.60992947626f         // TEMP_INV * log2(e)
#define NC2      (-20.60992947626f)      // shift: exp((dot-1)/T) = exp2(dot*KL2E + NC2)
#define NROWS 2048
#define DDIM 128

typedef __attribute__((ext_vector_type(8))) short bf16x8;
typedef __attribute__((ext_vector_type(4))) float f32x4;

// async global->LDS, 16B/lane; LDS dest = wave-uniform base + lane*16
#define GLOAD16(g, l) \
  __builtin_amdgcn_global_load_lds((const __attribute__((address_space(1))) void*)(g), \
                                   (__attribute__((address_space(3))) void*)(l), 16, 0, 0)

// ---------------- K1: cast fp32 [16,1024,2,128] -> bf16 contrast [16,2048,128]
__global__ __launch_bounds__(256) void cast_reorder_kernel(
    const float* __restrict__ feat, __hip_bfloat16* __restrict__ out)
{
    int t = blockIdx.x * blockDim.x + threadIdx.x;
    int e = t << 2;
    int d = e & 127;
    int v = (e >> 7) & 1;
    int i = (e >> 8) & 1023;
    int b = e >> 18;
    const float4 f = *reinterpret_cast<const float4*>(feat + e);
    union { __hip_bfloat16 h[4]; uint2 u; } o;
    o.h[0] = __float2bfloat16(f.x);
    o.h[1] = __float2bfloat16(f.y);
    o.h[2] = __float2bfloat16(f.z);
    o.h[3] = __float2bfloat16(f.w);
    size_t oe = (size_t)(((b << 11) + (v << 10) + i)) * DDIM + d;
    *reinterpret_cast<uint2*>(out + oe) = o.u;
}

// ---------------- K2: per-batch label-sum vectors Lsum[b][64][128] (f32)
// grid 16 (one block per batch) x 1024 thr; LDS histogram, plain stores.
__global__ __launch_bounds__(1024) void lsum_kernel(
    const __hip_bfloat16* __restrict__ contrast,
    const int* __restrict__ labels, float* __restrict__ Lsum)
{
    __shared__ float Ls[8192];        // 32 KB: 64 labels x 128 d
    const int tid = threadIdx.x;
    const int b = blockIdx.x;
    for (int k = tid; k < 8192; k += 1024) Ls[k] = 0.f;
    __syncthreads();
    const int d = tid & 127;          // column
    const int g = tid >> 7;           // row group 0..7
    const int* lb = labels + b * 1024;
    const __hip_bfloat16* cb = contrast + (size_t)b * NROWS * DDIM;
    for (int it = 0; it < 256; ++it) {
        const int row = g * 256 + it;
        const int lab = lb[row & 1023];     // wave-uniform scalar load
        const float v = __bfloat162float(cb[(size_t)row * DDIM + d]);
        atomicAdd(&Ls[lab * 128 + d], v);
    }
    __syncthreads();
    float* Lg = Lsum + b * 8192;
    for (int k = tid; k < 8192; k += 1024) Lg[k] = Ls[k];
}

// ---------------- K3: main exp-sum Gram GEMM (label-free, per-fc epilogue)
// grid 1024 = 16 b x 16 rb(128 rows) x 4 cs(512 cols). 4 waves stacked (32r each).
// B tiles 64c x 128d = 16KB dbuf, counted-vmcnt raw-barrier pipeline.
__global__ __launch_bounds__(256, 2) void supcon_main_kernel(
    const __hip_bfloat16* __restrict__ contrast,
    float* __restrict__ rsum_ws)
{
    __shared__ __align__(16) char lds[2][16384];

    const int tid  = threadIdx.x;
    const int lane = tid & 63;
    const int w    = tid >> 6;
    const int hi   = lane >> 4, lo = lane & 15;

    const int bid = blockIdx.x;
    const int xcd = bid & 7, idx = bid >> 3;
    const int b   = xcd * 2 + (idx >> 6);     // XCD owns 2 whole batches
    const int rem = idx & 63;
    const int rb  = rem >> 2;                 // 0..15: 128-row block
    const int cs  = rem & 3;                  // 0..3 : 512-col split

    const __hip_bfloat16* cbase = contrast + (size_t)b * NROWS * DDIM;

    // ---- prologue: stage A (128 rows) into lds[0](rows 0-63) + lds[1](rows 64-127)
    {
        char* abuf = (w < 2) ? &lds[0][0] : &lds[1][0];
        #pragma unroll
        for (int i = 0; i < 8; ++i) {
            const int cg  = w * 8 + i;                 // global chunk 0..31
            const int row = cg * 4 + hi;               // A row 0..127
            const int lc  = (w & 1) * 8 + i;           // chunk within buffer
            GLOAD16(cbase + (size_t)(rb * 128 + row) * DDIM + ((lo ^ (row & 7)) << 3),
                    abuf + lc * 1024);
        }
    }
    asm volatile("s_waitcnt vmcnt(0)\ns_barrier" ::: "memory");

    // ---- afrag: wave w owns rows w*32 .. +31 (fr 0..1)
    bf16x8 afrag[2][4];
    {
        const char* abase = (w < 2) ? &lds[0][0] : &lds[1][0];
        #pragma unroll
        for (int fr = 0; fr < 2; ++fr) {
            const int lr = (w & 1) * 32 + fr * 16 + lo;   // local row in buffer
            #pragma unroll
            for (int ks = 0; ks < 4; ++ks) {
                const int q = ks * 4 + hi;
                afrag[fr][ks] = *reinterpret_cast<const bf16x8*>(
                    abase + lr * 256 + ((q ^ (lo & 7)) << 4));
            }
        }
    }
    asm volatile("s_waitcnt lgkmcnt(0)\ns_barrier" ::: "memory");

    // ---- B staging pointers (wave stages 4KB/tile: rows (w*4+i)*4+hi)
    const __hip_bfloat16* gsrcB[4];
    #pragma unroll
    for (int i = 0; i < 4; ++i) {
        const int row = (w * 4 + i) * 4 + hi;          // 0..63 within B tile
        gsrcB[i] = cbase + (size_t)(cs * 512 + row) * DDIM + ((lo ^ (row & 7)) << 3);
    }
    // stage B0 -> lds[0]
    #pragma unroll
    for (int i = 0; i < 4; ++i) {
        GLOAD16(gsrcB[i], &lds[0][0] + (w * 4 + i) * 1024);
        gsrcB[i] += 64 * DDIM;
    }

    int bro[4];
    #pragma unroll
    for (int ks = 0; ks < 4; ++ks)
        bro[ks] = lo * 256 + (((ks * 4 + hi) ^ (lo & 7)) << 4);

    float se[2][4] = {{0,0,0,0},{0,0,0,0}};

// one phase: optional stage of next tile, counted-vmcnt barrier, 4 fc-quadrants
// each = {4 ds_read_b128, 8 MFMA, 8-elem epilogue} (acc live = 8 VGPRs only)
#define PHASE(CUR, STAGE)                                                        \
  {                                                                              \
    if (STAGE) {                                                                 \
      char* nbuf = &lds[(CUR) ^ 1][0];                                           \
      _Pragma("unroll")                                                          \
      for (int i = 0; i < 4; ++i) {                                              \
        GLOAD16(gsrcB[i], nbuf + (w * 4 + i) * 1024);                            \
        gsrcB[i] += 64 * DDIM;                                                   \
      }                                                                          \
      asm volatile("s_waitcnt vmcnt(4)\ns_barrier" ::: "memory");                \
    } else {                                                                     \
      asm volatile("s_waitcnt vmcnt(0)\ns_barrier" ::: "memory");                \
    }                                                                            \
    const char* base = &lds[CUR][0];                                             \
    _Pragma("unroll")                                                            \
    for (int fc = 0; fc < 4; ++fc) {                                             \
      bf16x8 bf[4];                                                              \
      _Pragma("unroll")                                                          \
      for (int ks = 0; ks < 4; ++ks)                                             \
        bf[ks] = *reinterpret_cast<const bf16x8*>(base + fc * 4096 + bro[ks]);   \
      f32x4 a0 = {0.f, 0.f, 0.f, 0.f}, a1 = {0.f, 0.f, 0.f, 0.f};                \
      _Pragma("unroll")                                                          \
      for (int ks = 0; ks < 4; ++ks) {                                           \
        a0 = __builtin_amdgcn_mfma_f32_16x16x32_bf16(afrag[0][ks], bf[ks], a0, 0, 0, 0); \
        a1 = __builtin_amdgcn_mfma_f32_16x16x32_bf16(afrag[1][ks], bf[ks], a1, 0, 0, 0); \
      }                                                                          \
      _Pragma("unroll")                                                          \
      for (int j = 0; j < 4; ++j) {                                              \
        se[0][j] += exp2f(fmaf(a0[j], KL2E, NC2));                               \
        se[1][j] += exp2f(fmaf(a1[j], KL2E, NC2));                               \
      }                                                                          \
    }                                                                            \
    asm volatile("s_barrier" ::: "memory");                                      \
  }

    PHASE(0, 1) PHASE(1, 1) PHASE(0, 1) PHASE(1, 1)
    PHASE(0, 1) PHASE(1, 1) PHASE(0, 1) PHASE(1, 0)
#undef PHASE

    // ---- reduce 16 col-lanes per row, atomicAdd per-row partials
    #pragma unroll
    for (int fr = 0; fr < 2; ++fr)
        #pragma unroll
        for (int j = 0; j < 4; ++j) {
            float s = se[fr][j];
            s += __shfl_xor(s, 1); s += __shfl_xor(s, 2);
            s += __shfl_xor(s, 4); s += __shfl_xor(s, 8);
            if (lo == 0)
                atomicAdd(&rsum_ws[b * NROWS + rb * 128 + w * 32 + fr * 16 + hi * 4 + j], s);
        }
}

// ---------------- K4: finalize — psum via Lsum, sd via |c|^2, loss assembly
// grid 256 = 16 b x 16 blocks(128 rows); 2 threads per row (d-halves).
__global__ __launch_bounds__(256) void finalize_kernel(
    const __hip_bfloat16* __restrict__ contrast,
    const int* __restrict__ labels,
    const float* __restrict__ rsum_ws, const float* __restrict__ Lsum,
    float* __restrict__ out)
{
    __shared__ int cnt_s[64];
    __shared__ float wred[4];
    const int tid = threadIdx.x, lane = tid & 63, wv = tid >> 6;
    const int b = blockIdx.x >> 4;
    const int rloc = (blockIdx.x & 15) * 128 + (tid >> 1);   // row in batch
    const int half = tid & 1;
    const int* lb = labels + b * 1024;

    if (tid < 64) cnt_s[tid] = 0;
    __syncthreads();
    for (int k = tid; k < 1024; k += 256) atomicAdd(&cnt_s[lb[k]], 1);
    __syncthreads();

    const int lab = lb[rloc & 1023];
    const __hip_bfloat16* crow = contrast + ((size_t)b * NROWS + rloc) * DDIM + half * 64;
    const float* L = Lsum + b * 8192 + lab * 128 + half * 64;

    float psum = 0.f, sd = 0.f;
    #pragma unroll
    for (int k = 0; k < 8; ++k) {
        bf16x8 cv = *reinterpret_cast<const bf16x8*>(crow + k * 8);
        #pragma unroll
        for (int e = 0; e < 8; ++e) {
            union { short s; unsigned short u; } uu; uu.s = cv[e];
            unsigned int bits = ((unsigned int)uu.u) << 16;
            float c; __builtin_memcpy(&c, &bits, 4);
            psum = fmaf(c, L[k * 8 + e], psum);
            sd   = fmaf(c, c, sd);
        }
    }
    psum += __shfl_xor(psum, 1);
    sd   += __shfl_xor(sd, 1);

    const float poscnt = (float)(2 * cnt_s[lab] - 1);        // >= 1
    const float P  = psum - sd;                              // exclude self
    const float rs = rsum_ws[b * NROWS + rloc] - exp2f(fmaf(sd, KL2E, NC2));
    float mlpp = P * TEMP_INV / poscnt - TEMP_INV - __logf(rs);

    #pragma unroll
    for (int o = 1; o < 64; o <<= 1) mlpp += __shfl_xor(mlpp, o);
    if (lane == 0) wred[wv] = mlpp;
    __syncthreads();
    if (tid == 0)   // each row counted twice (pair threads) -> /65536
        atomicAdd(out, -(wred[0] + wred[1] + wred[2] + wred[3]) * (1.0f / 65536.0f));
}

extern "C" void kernel_launch(void* const* d_in, const int* in_sizes, int n_in,
                              void* d_out, int out_size, void* d_ws, size_t ws_size,
                              hipStream_t stream) {
    const float* feat = (const float*)d_in[0];
    const int* labels = (const int*)d_in[1];
    float* out = (float*)d_out;

    char* ws = (char*)d_ws;
    __hip_bfloat16* contrast = (__hip_bfloat16*)ws;     // 8,388,608 B
    float* rsum_ws = (float*)(ws + 8388608);            // 131,072 B (atomic target)
    float* Lsum_ws = (float*)(ws + 8519680);            // 524,288 B (plain stores)

    hipMemsetAsync(d_out, 0, sizeof(float), stream);
    hipMemsetAsync(ws + 8388608, 0, 131072, stream);
    cast_reorder_kernel<<<4096, 256, 0, stream>>>(feat, contrast);
    lsum_kernel<<<16, 1024, 0, stream>>>(contrast, labels, Lsum_ws);
    supcon_main_kernel<<<1024, 256, 0, stream>>>(contrast, rsum_ws);
    finalize_kernel<<<256, 256, 0, stream>>>(contrast, labels, rsum_ws, Lsum_ws, out);
}

// Round 10
// 214.167 us; speedup vs baseline: 2.0995x; 2.0995x over previous
//
#include <hip/hip_runtime.h>
#include <hip/hip_bf16.h>

#define TEMP_INV 14.285714285714286f     // 1/0.07
#define KL2E     20.60992947626f         // TEMP_INV * log2(e)
#define NC2      (-20.60992947626f)      // shift: exp((dot-1)/T) = exp2(dot*KL2E + NC2)
#define NROWS 2048
#define DDIM 128

typedef __attribute__((ext_vector_type(8))) short bf16x8;
typedef __attribute__((ext_vector_type(4))) float f32x4;

// async global->LDS, 16B/lane; LDS dest = wave-uniform base + lane*16
#define GLOAD16(g, l) \
  __builtin_amdgcn_global_load_lds((const __attribute__((address_space(1))) void*)(g), \
                                   (__attribute__((address_space(3))) void*)(l), 16, 0, 0)

// ---------------- K1: cast fp32 [16,1024,2,128] -> bf16 contrast [16,2048,128]
__global__ __launch_bounds__(256) void cast_reorder_kernel(
    const float* __restrict__ feat, __hip_bfloat16* __restrict__ out)
{
    int t = blockIdx.x * blockDim.x + threadIdx.x;
    int e = t << 2;
    int d = e & 127;
    int v = (e >> 7) & 1;
    int i = (e >> 8) & 1023;
    int b = e >> 18;
    const float4 f = *reinterpret_cast<const float4*>(feat + e);
    union { __hip_bfloat16 h[4]; uint2 u; } o;
    o.h[0] = __float2bfloat16(f.x);
    o.h[1] = __float2bfloat16(f.y);
    o.h[2] = __float2bfloat16(f.z);
    o.h[3] = __float2bfloat16(f.w);
    size_t oe = (size_t)(((b << 11) + (v << 10) + i)) * DDIM + d;
    *reinterpret_cast<uint2*>(out + oe) = o.u;
}

// ---------------- K2: per-(batch,seg) label-sum partials Lpart[b][4][64][128]
// grid 64 = 16 b x 4 segs(512 rows); 256 thr. LDS histogram, plain stores out.
__global__ __launch_bounds__(256) void lsum_kernel(
    const __hip_bfloat16* __restrict__ contrast,
    const int* __restrict__ labels, float* __restrict__ Lpart)
{
    __shared__ float Ls[8192];        // 32 KB: 64 labels x 128 d
    __shared__ int slab[512];
    const int tid = threadIdx.x;
    const int b = blockIdx.x >> 2, seg = blockIdx.x & 3;
    for (int k = tid; k < 8192; k += 256) Ls[k] = 0.f;
    for (int k = tid; k < 512; k += 256) slab[k] = labels[b * 1024 + (seg & 1) * 512 + k];
    __syncthreads();
    const int d = tid & 127, g = tid >> 7;     // g: 0..1
    const __hip_bfloat16* cb = contrast + (size_t)b * NROWS * DDIM;
    for (int it = 0; it < 256; ++it) {
        const int rl  = g * 256 + it;          // 0..511 local row
        const int row = seg * 512 + rl;
        const int lab = slab[rl];
        const float v = __bfloat162float(cb[(size_t)row * DDIM + d]);
        atomicAdd(&Ls[lab * 128 + d], v);
    }
    __syncthreads();
    float* Lg = Lpart + (size_t)(b * 4 + seg) * 8192;
    for (int k = tid; k < 8192; k += 256) Lg[k] = Ls[k];
}

// ---------------- K3: main exp-sum Gram GEMM (label-free, per-fc epilogue)
// grid 1024 = 16 b x 16 rb(128 rows) x 4 cs(512 cols). 4 waves stacked (32r each).
// B tiles 64c x 128d = 16KB dbuf, counted-vmcnt raw-barrier pipeline.
__global__ __launch_bounds__(256, 2) void supcon_main_kernel(
    const __hip_bfloat16* __restrict__ contrast,
    float* __restrict__ rsum_ws)
{
    __shared__ __align__(16) char lds[2][16384];

    const int tid  = threadIdx.x;
    const int lane = tid & 63;
    const int w    = tid >> 6;
    const int hi   = lane >> 4, lo = lane & 15;

    const int bid = blockIdx.x;
    const int xcd = bid & 7, idx = bid >> 3;
    const int b   = xcd * 2 + (idx >> 6);     // XCD owns 2 whole batches
    const int rem = idx & 63;
    const int rb  = rem >> 2;                 // 0..15: 128-row block
    const int cs  = rem & 3;                  // 0..3 : 512-col split

    const __hip_bfloat16* cbase = contrast + (size_t)b * NROWS * DDIM;

    // ---- prologue: stage A (128 rows) into lds[0](rows 0-63) + lds[1](rows 64-127)
    {
        char* abuf = (w < 2) ? &lds[0][0] : &lds[1][0];
        #pragma unroll
        for (int i = 0; i < 8; ++i) {
            const int cg  = w * 8 + i;                 // global chunk 0..31
            const int row = cg * 4 + hi;               // A row 0..127
            const int lc  = (w & 1) * 8 + i;           // chunk within buffer
            GLOAD16(cbase + (size_t)(rb * 128 + row) * DDIM + ((lo ^ (row & 7)) << 3),
                    abuf + lc * 1024);
        }
    }
    asm volatile("s_waitcnt vmcnt(0)\ns_barrier" ::: "memory");

    // ---- afrag: wave w owns rows w*32 .. +31 (fr 0..1)
    bf16x8 afrag[2][4];
    {
        const char* abase = (w < 2) ? &lds[0][0] : &lds[1][0];
        #pragma unroll
        for (int fr = 0; fr < 2; ++fr) {
            const int lr = (w & 1) * 32 + fr * 16 + lo;   // local row in buffer
            #pragma unroll
            for (int ks = 0; ks < 4; ++ks) {
                const int q = ks * 4 + hi;
                afrag[fr][ks] = *reinterpret_cast<const bf16x8*>(
                    abase + lr * 256 + ((q ^ (lo & 7)) << 4));
            }
        }
    }
    asm volatile("s_waitcnt lgkmcnt(0)\ns_barrier" ::: "memory");

    // ---- B staging pointers (wave stages 4KB/tile: rows (w*4+i)*4+hi)
    const __hip_bfloat16* gsrcB[4];
    #pragma unroll
    for (int i = 0; i < 4; ++i) {
        const int row = (w * 4 + i) * 4 + hi;          // 0..63 within B tile
        gsrcB[i] = cbase + (size_t)(cs * 512 + row) * DDIM + ((lo ^ (row & 7)) << 3);
    }
    // stage B0 -> lds[0]
    #pragma unroll
    for (int i = 0; i < 4; ++i) {
        GLOAD16(gsrcB[i], &lds[0][0] + (w * 4 + i) * 1024);
        gsrcB[i] += 64 * DDIM;
    }

    int bro[4];
    #pragma unroll
    for (int ks = 0; ks < 4; ++ks)
        bro[ks] = lo * 256 + (((ks * 4 + hi) ^ (lo & 7)) << 4);

    float se[2][4] = {{0,0,0,0},{0,0,0,0}};

// one phase: optional stage of next tile, counted-vmcnt barrier, 4 fc-quadrants
// each = {4 ds_read_b128, 8 MFMA, 8-elem epilogue} (acc live = 8 VGPRs only)
#define PHASE(CUR, STAGE)                                                        \
  {                                                                              \
    if (STAGE) {                                                                 \
      char* nbuf = &lds[(CUR) ^ 1][0];                                           \
      _Pragma("unroll")                                                          \
      for (int i = 0; i < 4; ++i) {                                              \
        GLOAD16(gsrcB[i], nbuf + (w * 4 + i) * 1024);                            \
        gsrcB[i] += 64 * DDIM;                                                   \
      }                                                                          \
      asm volatile("s_waitcnt vmcnt(4)\ns_barrier" ::: "memory");                \
    } else {                                                                     \
      asm volatile("s_waitcnt vmcnt(0)\ns_barrier" ::: "memory");                \
    }                                                                            \
    const char* base = &lds[CUR][0];                                             \
    _Pragma("unroll")                                                            \
    for (int fc = 0; fc < 4; ++fc) {                                             \
      bf16x8 bf[4];                                                              \
      _Pragma("unroll")                                                          \
      for (int ks = 0; ks < 4; ++ks)                                             \
        bf[ks] = *reinterpret_cast<const bf16x8*>(base + fc * 4096 + bro[ks]);   \
      f32x4 a0 = {0.f, 0.f, 0.f, 0.f}, a1 = {0.f, 0.f, 0.f, 0.f};                \
      _Pragma("unroll")                                                          \
      for (int ks = 0; ks < 4; ++ks) {                                           \
        a0 = __builtin_amdgcn_mfma_f32_16x16x32_bf16(afrag[0][ks], bf[ks], a0, 0, 0, 0); \
        a1 = __builtin_amdgcn_mfma_f32_16x16x32_bf16(afrag[1][ks], bf[ks], a1, 0, 0, 0); \
      }                                                                          \
      _Pragma("unroll")                                                          \
      for (int j = 0; j < 4; ++j) {                                              \
        se[0][j] += exp2f(fmaf(a0[j], KL2E, NC2));                               \
        se[1][j] += exp2f(fmaf(a1[j], KL2E, NC2));                               \
      }                                                                          \
    }                                                                            \
    asm volatile("s_barrier" ::: "memory");                                      \
  }

    PHASE(0, 1) PHASE(1, 1) PHASE(0, 1) PHASE(1, 1)
    PHASE(0, 1) PHASE(1, 1) PHASE(0, 1) PHASE(1, 0)
#undef PHASE

    // ---- reduce 16 col-lanes per row, atomicAdd per-row partials
    #pragma unroll
    for (int fr = 0; fr < 2; ++fr)
        #pragma unroll
        for (int j = 0; j < 4; ++j) {
            float s = se[fr][j];
            s += __shfl_xor(s, 1); s += __shfl_xor(s, 2);
            s += __shfl_xor(s, 4); s += __shfl_xor(s, 8);
            if (lo == 0)
                atomicAdd(&rsum_ws[b * NROWS + rb * 128 + w * 32 + fr * 16 + hi * 4 + j], s);
        }
}

// ---------------- K4: finalize — psum via 4 Lpart segs, sd via |c|^2, loss
// grid 256 = 16 b x 16 blocks(128 rows); 2 threads per row (d-halves).
__global__ __launch_bounds__(256) void finalize_kernel(
    const __hip_bfloat16* __restrict__ contrast,
    const int* __restrict__ labels,
    const float* __restrict__ rsum_ws, const float* __restrict__ Lpart,
    float* __restrict__ out)
{
    __shared__ int cnt_s[64];
    __shared__ float wred[4];
    const int tid = threadIdx.x, lane = tid & 63, wv = tid >> 6;
    const int b = blockIdx.x >> 4;
    const int rloc = (blockIdx.x & 15) * 128 + (tid >> 1);   // row in batch
    const int half = tid & 1;
    const int* lb = labels + b * 1024;

    if (tid < 64) cnt_s[tid] = 0;
    __syncthreads();
    for (int k = tid; k < 1024; k += 256) atomicAdd(&cnt_s[lb[k]], 1);
    __syncthreads();

    const int lab = lb[rloc & 1023];
    const __hip_bfloat16* crow = contrast + ((size_t)b * NROWS + rloc) * DDIM + half * 64;
    const float* L0 = Lpart + (size_t)(b * 4) * 8192 + lab * 128 + half * 64;

    float psum = 0.f, sd = 0.f;
    #pragma unroll
    for (int k = 0; k < 8; ++k) {
        bf16x8 cv = *reinterpret_cast<const bf16x8*>(crow + k * 8);
        #pragma unroll
        for (int e = 0; e < 8; ++e) {
            union { short s; unsigned short u; } uu; uu.s = cv[e];
            unsigned int bits = ((unsigned int)uu.u) << 16;
            float c; __builtin_memcpy(&c, &bits, 4);
            const int o = k * 8 + e;
            const float Lt = L0[o] + L0[8192 + o] + L0[16384 + o] + L0[24576 + o];
            psum = fmaf(c, Lt, psum);
            sd   = fmaf(c, c, sd);
        }
    }
    psum += __shfl_xor(psum, 1);
    sd   += __shfl_xor(sd, 1);

    const float poscnt = (float)(2 * cnt_s[lab] - 1);        // >= 1
    const float P  = psum - sd;                              // exclude self
    const float rs = rsum_ws[b * NROWS + rloc] - exp2f(fmaf(sd, KL2E, NC2));
    float mlpp = P * TEMP_INV / poscnt - TEMP_INV - __logf(rs);

    #pragma unroll
    for (int o = 1; o < 64; o <<= 1) mlpp += __shfl_xor(mlpp, o);
    if (lane == 0) wred[wv] = mlpp;
    __syncthreads();
    if (tid == 0)   // each row counted twice (pair threads) -> /65536
        atomicAdd(out, -(wred[0] + wred[1] + wred[2] + wred[3]) * (1.0f / 65536.0f));
}

extern "C" void kernel_launch(void* const* d_in, const int* in_sizes, int n_in,
                              void* d_out, int out_size, void* d_ws, size_t ws_size,
                              hipStream_t stream) {
    const float* feat = (const float*)d_in[0];
    const int* labels = (const int*)d_in[1];
    float* out = (float*)d_out;

    char* ws = (char*)d_ws;
    __hip_bfloat16* contrast = (__hip_bfloat16*)ws;     // 8,388,608 B
    float* rsum_ws = (float*)(ws + 8388608);            // 131,072 B (atomic target)
    float* Lpart_ws = (float*)(ws + 8519680);           // 2,097,152 B (plain stores)

    hipMemsetAsync(d_out, 0, sizeof(float), stream);
    hipMemsetAsync(ws + 8388608, 0, 131072, stream);
    cast_reorder_kernel<<<4096, 256, 0, stream>>>(feat, contrast);
    lsum_kernel<<<64, 256, 0, stream>>>(contrast, labels, Lpart_ws);
    supcon_main_kernel<<<1024, 256, 0, stream>>>(contrast, rsum_ws);
    finalize_kernel<<<256, 256, 0, stream>>>(contrast, labels, rsum_ws, Lpart_ws, out);
}